// Round 3
// baseline (124.611 us; speedup 1.0000x reference)
//
#include <hip/hip_runtime.h>
#include <math.h>

#define BINS 10

// Problem constants: BATCH=8388608, NUM_CLASSES=2
constexpr int   NPAIRS = 4194304;       // float4 quads (2 rows x 2 classes each)
constexpr float NTOT_F = 16777216.0f;   // BATCH * NUM_CLASSES

constexpr int G1     = 2048;            // 8 blocks/CU -> 100% occupancy (LDS 20 KB/block)
constexpr int BLK    = 256;
constexpr int STRIDE = G1 * BLK;        // 524288
constexpr int ITERS  = NPAIRS / STRIDE; // 8, exact -> fully unrollable, no tail

// Workspace (written before read; no memset needed):
constexpr size_t WS_SUM = 0;            // f32 [BINS][G1] = 81920 B
constexpr size_t WS_CNT = 81920;        // u32 [BINS][G1] = 81920 B

struct alignas(8) Pair { float s; unsigned c; };   // one ds_*_b64 RMW per element

__device__ __forceinline__ void proc(float x, bool y1, int tid,
                                     Pair* __restrict__ lds) {
    // z = (y==1) ? -x : x ; t = e^z ; u = 1+t
    // g = |sigmoid(x)-y| = t/u ; bce = max(x,0)-x*y+log1p(e^-|x|) = ln(u) = ln2*log2(u)
    float z = y1 ? -x : x;
    float t = __builtin_amdgcn_exp2f(z * 1.4426950408889634f);
    float u = 1.0f + t;
    float g = t * __builtin_amdgcn_rcpf(u);
    int   b = (int)(g * 9.9999f);        // g in [0,1] -> trunc == floor
    b = b < 9 ? b : 9;                   // clamp (rcp rounding can push g epsilon over 1)
    float l = __builtin_amdgcn_logf(u);  // log2(u); ln2 applied once at the very end
    Pair  p = lds[b * BLK + tid];        // ds_read_b64
    p.s += l;
    p.c += 1u;
    lds[b * BLK + tid] = p;              // ds_write_b64
}

// Single data pass. LDS columns lds[bin*256+tid]: per-thread private until the
// block reduce -> no intra-loop barrier, no cross-thread conflicts (b64 width
// cost only). Counted loop of 8 iters, fully unrolled -> loads hoisted/pipelined.
__global__ __launch_bounds__(BLK) void ghm_main(const float4* __restrict__ x4,
                                                const int2*   __restrict__ t2,
                                                float*        __restrict__ blk_sum,
                                                unsigned*     __restrict__ blk_cnt) {
    __shared__ Pair lds[BINS * BLK];     // 20480 B
    const int tid = threadIdx.x;

#pragma unroll
    for (int b = 0; b < BINS; ++b) lds[b * BLK + tid] = Pair{0.0f, 0u};
    // no barrier: each thread touches only its own columns until the reduce

    const int base = blockIdx.x * BLK + tid;
#pragma unroll
    for (int k = 0; k < ITERS; ++k) {
        float4 xv = x4[base + k * STRIDE];
        int2   tv = t2[base + k * STRIDE];
        // element (row, c): y = (target[row] == c)
        proc(xv.x, tv.x == 0, tid, lds);
        proc(xv.y, tv.x == 1, tid, lds);
        proc(xv.z, tv.y == 0, tid, lds);
        proc(xv.w, tv.y == 1, tid, lds);
    }

    __syncthreads();
    const int wave = tid >> 6;
    const int lane = tid & 63;
    // wave w reduces bins {w, w+4, w+8}: 4 strided pair reads + 64-lane shuffle tree
    for (int b = wave; b < BINS; b += 4) {
        Pair p0 = lds[b * BLK + lane];
        Pair p1 = lds[b * BLK + lane + 64];
        Pair p2 = lds[b * BLK + lane + 128];
        Pair p3 = lds[b * BLK + lane + 192];
        float    s = p0.s + p1.s + p2.s + p3.s;
        unsigned c = p0.c + p1.c + p2.c + p3.c;
        for (int off = 32; off > 0; off >>= 1) {
            s += __shfl_down(s, off, 64);
            c += __shfl_down(c, off, 64);
        }
        if (lane == 0) {
            blk_sum[b * G1 + blockIdx.x] = s;   // bin-major -> contiguous for final
            blk_cnt[b * G1 + blockIdx.x] = c;
        }
    }
}

// Final: 10 waves, wave w reduces bin w's G1 partials (f64), then thread 0 forms
// beta per reference fp32 arithmetic and the weighted total. Deterministic.
__global__ __launch_bounds__(640) void ghm_final(const float*    __restrict__ blk_sum,
                                                 const unsigned* __restrict__ blk_cnt,
                                                 float*          __restrict__ out) {
    const int wave = threadIdx.x >> 6;   // 0..9 = bin
    const int lane = threadIdx.x & 63;
    double s = 0.0, c = 0.0;
    for (int g = lane; g < G1; g += 64) {
        s += (double)blk_sum[wave * G1 + g];
        c += (double)blk_cnt[wave * G1 + g];
    }
    for (int off = 32; off > 0; off >>= 1) {
        s += __shfl_down(s, off, 64);
        c += __shfl_down(c, off, 64);
    }
    __shared__ double Sb[BINS], Cb[BINS];
    if (lane == 0) { Sb[wave] = s; Cb[wave] = c; }
    __syncthreads();
    if (threadIdx.x == 0) {
        float nonempty = 0.0f;
#pragma unroll
        for (int b = 0; b < BINS; ++b) nonempty += (Cb[b] > 0.0) ? 1.0f : 0.0f;
        double tot = 0.0;
#pragma unroll
        for (int b = 0; b < BINS; ++b) {
            float gd   = fmaxf((float)Cb[b] * nonempty, 0.0001f);  // ref fp32 math
            float beta = NTOT_F / gd;
            tot += (double)beta * Sb[b];
        }
        // bce sums kept in log2; apply ln2 once, then mean
        out[0] = (float)(tot * 0.693147180559945309 / (double)NTOT_F);
    }
}

extern "C" void kernel_launch(void* const* d_in, const int* in_sizes, int n_in,
                              void* d_out, int out_size, void* d_ws, size_t ws_size,
                              hipStream_t stream) {
    const float4* x4 = (const float4*)d_in[0];   // [B,2] fp32 -> 2 rows per float4
    const int2*   t2 = (const int2*)d_in[1];     // int32 targets -> 2 rows per int2

    float*    blk_sum = (float*)   ((char*)d_ws + WS_SUM);
    unsigned* blk_cnt = (unsigned*)((char*)d_ws + WS_CNT);
    float*    out     = (float*)d_out;

    ghm_main <<<G1, BLK, 0, stream>>>(x4, t2, blk_sum, blk_cnt);
    ghm_final<<<1, 640, 0, stream>>>(blk_sum, blk_cnt, out);
}